// Round 12
// baseline (343.741 us; speedup 1.0000x reference)
//
#include <hip/hip_runtime.h>
#include <math.h>

// Problem constants
#define D 64
#define HWD 4096          // 64*64
#define NVEC 131072       // 32*64*64
#define K 1024

// d_out layout (float element offsets: loss, out, perplexity, encodings, inputs)
// NOTE: O_ENC % 4 == 2 and O_INP % 4 == 2 -> 16B-aligned chunks sit at
// column offsets == 2 (mod 4).
#define O_LOSS 0
#define O_OUT  1
#define O_PERP 8388609ULL
#define O_ENC  8388610ULL
#define O_INP  142606338ULL   // 8388610 + 134217728

// d_ws layout (bytes)
#define WS_CBH   0          // K*D fp16 B-fragment-packed (131072 B)
#define WS_CBL   131072     // K*D fp16 lo part           (131072 B)
#define WS_C2    262144     // 1024 float                 (4096 B)
#define WS_HIST  266240     // 1024 int                   (4096 B)
#define WS_LPART 270336     // 2048 float                 (8192 B)
#define WS_IDX   278528     // 131072 ushort              (262144 B)

typedef _Float16 half8 __attribute__((ext_vector_type(8)));
typedef float    f32x16 __attribute__((ext_vector_type(16)));
typedef float    f32x4  __attribute__((ext_vector_type(4)));
typedef float    f32x2  __attribute__((ext_vector_type(2)));

// ---------------------------------------------------------------------------
// Fused prep: blocks 0-31 pack codebook into MFMA B-fragment layout (fp16
// hi/lo); blocks 32-35 compute ||c||^2 (fp32 exact).
__global__ __launch_bounds__(256) void prep_kernel(const float* __restrict__ cb,
                                                   _Float16* __restrict__ cbh,
                                                   _Float16* __restrict__ cbl,
                                                   float* __restrict__ c2) {
    if (blockIdx.x < 32) {
        int u  = blockIdx.x * 256 + threadIdx.x;   // 8192 units
        int l  = u & 63;
        int s  = (u >> 6) & 3;
        int kt = u >> 8;
        int k  = kt * 32 + (l & 31);
        int d0 = s * 16 + (l >> 5) * 8;
        const float* src = cb + k * D + d0;
        half8 h, lo;
        #pragma unroll
        for (int i = 0; i < 8; ++i) {
            float v = src[i];
            _Float16 hh = (_Float16)v;
            h[i]  = hh;
            lo[i] = (_Float16)(v - (float)hh);
        }
        reinterpret_cast<half8*>(cbh)[u] = h;
        reinterpret_cast<half8*>(cbl)[u] = lo;
    } else {
        int k = (blockIdx.x - 32) * 256 + threadIdx.x;
        const float4* row = reinterpret_cast<const float4*>(cb + k * D);
        float s = 0.f;
        #pragma unroll
        for (int q = 0; q < 16; ++q) {
            float4 c = row[q];
            s = fmaf(c.x, c.x, s); s = fmaf(c.y, c.y, s);
            s = fmaf(c.z, c.z, s); s = fmaf(c.w, c.w, s);
        }
        c2[k] = s;
    }
}

// ---------------------------------------------------------------------------
// PURE compute kernel — NO bulk stores. Per block = 64 rows, 4 waves
// partition K. Outputs only: idx (ushort), histogram atomics, loss partials.
// This isolates the MFMA/argmin pipeline from the store streams entirely.
__global__ __launch_bounds__(256, 2) void vq_core(
    const float* __restrict__ x,
    const _Float16* __restrict__ cbh, const _Float16* __restrict__ cbl,
    const float* __restrict__ c2,
    unsigned short* __restrict__ idxg,
    int* __restrict__ hist, float* __restrict__ lossPart)
{
    __shared__ float    sb[4][64];
    __shared__ unsigned sk[4][64];
    __shared__ float    ssx[64];

    const int lane = threadIdx.x & 63;
    const int wid  = threadIdx.x >> 6;
    const int col  = lane & 31;
    const int g    = lane >> 5;
    const int n0   = blockIdx.x * 64;
    const int b    = n0 >> 12;
    const int hw0  = n0 & 4095;
    const size_t bbase = (size_t)b << 18;   // b * D * HWD

    // ---- Phase 0: x load + immediate fp16 hi/lo convert (xv dies here)
    half8 ah[2][4], al[2][4];
    float sx2[2] = {0.f, 0.f};
    #pragma unroll
    for (int m = 0; m < 2; ++m) {
        const float* xp = x + bbase + (hw0 + m * 32 + col);
        #pragma unroll
        for (int s = 0; s < 4; ++s) {
            #pragma unroll
            for (int i = 0; i < 8; ++i) {
                float v = xp[(size_t)(s * 16 + g * 8 + i) << 12];
                sx2[m] = fmaf(v, v, sx2[m]);
                _Float16 h = (_Float16)v;
                ah[m][s][i] = h;
                al[m][s][i] = (_Float16)(v - (float)h);
            }
        }
    }
    #pragma unroll
    for (int m = 0; m < 2; ++m) {
        float sp = sx2[m] + __shfl_xor(sx2[m], 32, 64);
        if (wid == 0 && g == 0) ssx[m * 32 + col] = sp;
    }

    // ---- Phase 1: MFMA argmin. score = ||c||^2 - 2 x.c
    float    best[2][16];
    unsigned kbest[2][16];
    #pragma unroll
    for (int m = 0; m < 2; ++m)
        #pragma unroll
        for (int r = 0; r < 16; ++r) { best[m][r] = 3.4e38f; kbest[m][r] = 0u; }

    const half8* Bh = reinterpret_cast<const half8*>(cbh);
    const half8* Bl = reinterpret_cast<const half8*>(cbl);

    for (int j = 0; j < 8; ++j) {
        int kt = wid * 8 + j;                  // this wave's 32-code tile
        half8 bh[4], bl_[4];
        #pragma unroll
        for (int s = 0; s < 4; ++s) {
            bh[s]  = Bh[(kt * 4 + s) * 64 + lane];   // coalesced, L2-resident
            bl_[s] = Bl[(kt * 4 + s) * 64 + lane];
        }
        float    c2v  = c2[kt * 32 + col];
        unsigned kcur = (unsigned)(kt * 32 + col);

        f32x16 a0, a1;
        #pragma unroll
        for (int r = 0; r < 16; ++r) { a0[r] = 0.f; a1[r] = 0.f; }

        #pragma unroll
        for (int s = 0; s < 4; ++s) {
            a0 = __builtin_amdgcn_mfma_f32_32x32x16_f16(ah[0][s], bh[s],  a0, 0, 0, 0);
            a1 = __builtin_amdgcn_mfma_f32_32x32x16_f16(ah[1][s], bh[s],  a1, 0, 0, 0);
            a0 = __builtin_amdgcn_mfma_f32_32x32x16_f16(al[0][s], bh[s],  a0, 0, 0, 0);
            a1 = __builtin_amdgcn_mfma_f32_32x32x16_f16(al[1][s], bh[s],  a1, 0, 0, 0);
            a0 = __builtin_amdgcn_mfma_f32_32x32x16_f16(ah[0][s], bl_[s], a0, 0, 0, 0);
            a1 = __builtin_amdgcn_mfma_f32_32x32x16_f16(ah[1][s], bl_[s], a1, 0, 0, 0);
        }

        #pragma unroll
        for (int r = 0; r < 16; ++r) {
            float s0 = fmaf(-2.0f, a0[r], c2v);
            if (s0 < best[0][r]) { best[0][r] = s0; kbest[0][r] = kcur; }
            float s1 = fmaf(-2.0f, a1[r], c2v);
            if (s1 < best[1][r]) { best[1][r] = s1; kbest[1][r] = kcur; }
        }
    }

    // Per-wave cross-lane argmin over the 32 cols
    #pragma unroll
    for (int m = 0; m < 2; ++m) {
        #pragma unroll
        for (int r = 0; r < 16; ++r) {
            float bv = best[m][r]; unsigned kv = kbest[m][r];
            #pragma unroll
            for (int mask = 1; mask <= 16; mask <<= 1) {
                float    ob = __shfl_xor(bv, mask);
                unsigned ok = (unsigned)__shfl_xor((int)kv, mask);
                if (ob < bv || (ob == bv && ok < kv)) { bv = ob; kv = ok; }
            }
            if (col == 0) {
                int row = (r & 3) + 8 * (r >> 2) + 4 * g;   // C layout (m74/m101)
                sb[wid][m * 32 + row] = bv;
                sk[wid][m * 32 + row] = kv;
            }
        }
    }
    __syncthreads();

    // ---- Phase 2: cross-wave combine -> idx, loss partial, histogram
    if (threadIdx.x < 64) {
        int t = threadIdx.x;
        float bv = sb[0][t]; unsigned kv = sk[0][t];
        #pragma unroll
        for (int w = 1; w < 4; ++w) {
            float ob = sb[w][t];
            if (ob < bv) { bv = ob; kv = sk[w][t]; }
        }
        idxg[n0 + t] = (unsigned short)kv;
        atomicAdd(&hist[kv], 1);
        float lp = bv + ssx[t];                 // ||c-x||^2 = score + ||x||^2
        #pragma unroll
        for (int off = 32; off > 0; off >>= 1) lp += __shfl_down(lp, off, 64);
        if (t == 0) lossPart[blockIdx.x] = lp;
    }
}

// ---------------------------------------------------------------------------
// Dedicated streaming kernel: ALL bulk outputs from idx. Per block = 64 rows.
//   (a) one-hot encodings (zeros + one folded via compare), nt stores
//   (b) inputs NHWC (reads x strided, writes contiguous)
//   (c) quantized NCHW (gather codebook rows)
// Pure store pipeline: no MFMA, no barriers, minimal VALU.
__global__ __launch_bounds__(256) void streams_kernel(
    const float* __restrict__ x, const float* __restrict__ cb,
    const unsigned short* __restrict__ idx, float* __restrict__ out)
{
    const int lane = threadIdx.x & 63;
    const int wid  = threadIdx.x >> 6;
    const int n0   = blockIdx.x * 64;
    const int b    = n0 >> 12;
    const int hw0  = n0 & 4095;
    const size_t bbase = (size_t)b << 18;

    // Wave-local idx table: lane l holds k of row n0+l
    unsigned kvreg = idx[n0 + lane];

    // ---- (a) encodings: wave w writes rows w, w+4, ..., w+60 (16 rows)
    {
        float* rp = out + O_ENC + (size_t)(n0 + wid) * K;
        #pragma unroll
        for (int j = 0; j < 16; ++j) {
            int r   = wid + 4 * j;
            int skr = __builtin_amdgcn_readlane((int)kvreg, r);
            float* rpj = rp + (size_t)(4 * j) * K;
            #pragma unroll
            for (int q = 0; q < 4; ++q) {
                int t  = q * 64 + lane;       // chunk id 0..255
                int c0 = 2 + 4 * t;
                if (t < 255) {
                    f32x4 v = {(float)(c0 == skr), (float)(c0 + 1 == skr),
                               (float)(c0 + 2 == skr), (float)(c0 + 3 == skr)};
                    __builtin_nontemporal_store(v, reinterpret_cast<f32x4*>(rpj + c0));
                } else {
                    f32x2 h2 = {(float)(0 == skr), (float)(1 == skr)};
                    f32x2 t2 = {(float)(1022 == skr), (float)(1023 == skr)};
                    __builtin_nontemporal_store(h2, reinterpret_cast<f32x2*>(rpj));
                    __builtin_nontemporal_store(t2, reinterpret_cast<f32x2*>(rpj + 1022));
                }
            }
        }
    }

    // ---- (b) inputs NHWC: thread t -> row n0 + (t>>2), d-chunk (t&3)*16
    {
        int r  = threadIdx.x >> 2;
        int s  = threadIdx.x & 3;
        const float* xp = x + bbase + (hw0 + r) + ((size_t)(s * 16) << 12);
        float v[16];
        #pragma unroll
        for (int i = 0; i < 16; ++i) v[i] = xp[(size_t)i << 12];
        float* ip = out + O_INP + (size_t)(n0 + r) * 64 + s * 16;
        // abs base == 2 (mod 4): x2 | x4 x4 x4 | x2
        f32x2 h2 = {v[0], v[1]};
        f32x4 a4 = {v[2], v[3], v[4], v[5]};
        f32x4 b4 = {v[6], v[7], v[8], v[9]};
        f32x4 c4 = {v[10], v[11], v[12], v[13]};
        f32x2 t2 = {v[14], v[15]};
        __builtin_nontemporal_store(h2, reinterpret_cast<f32x2*>(ip));
        __builtin_nontemporal_store(a4, reinterpret_cast<f32x4*>(ip + 2));
        __builtin_nontemporal_store(b4, reinterpret_cast<f32x4*>(ip + 6));
        __builtin_nontemporal_store(c4, reinterpret_cast<f32x4*>(ip + 10));
        __builtin_nontemporal_store(t2, reinterpret_cast<f32x2*>(ip + 14));
    }

    // ---- (c) quantized NCHW: lane -> row, wave w -> 16 channels
    {
        unsigned kr = kvreg;                  // lane l = row l
        const float* crow = cb + (size_t)kr * D;
        float* ob = out + O_OUT + bbase + hw0 + lane;
        #pragma unroll
        for (int c16 = 0; c16 < 16; ++c16) {
            int c = wid * 16 + c16;
            __builtin_nontemporal_store(crow[c], ob + ((size_t)c << 12));
        }
    }
}

// ---------------------------------------------------------------------------
// Scalars: perplexity from histogram, loss from 2048 partials
__global__ __launch_bounds__(1024) void final_kernel(
    const int* __restrict__ hist, const float* __restrict__ lossPart,
    float* __restrict__ out)
{
    __shared__ float red[1024];
    int t = threadIdx.x;

    float p = (float)hist[t] * (1.0f / (float)NVEC);
    red[t] = p * logf(p + 1e-10f);
    __syncthreads();
    for (int s = 512; s > 0; s >>= 1) {
        if (t < s) red[t] += red[t + s];
        __syncthreads();
    }
    float perp = expf(-red[0]);
    __syncthreads();

    red[t] = lossPart[t] + lossPart[t + 1024];
    __syncthreads();
    for (int s = 512; s > 0; s >>= 1) {
        if (t < s) red[t] += red[t + s];
        __syncthreads();
    }
    if (t == 0) {
        out[O_PERP] = perp;
        out[O_LOSS] = 0.25f * red[0] / 8388608.0f;
    }
}

// ---------------------------------------------------------------------------
extern "C" void kernel_launch(void* const* d_in, const int* in_sizes, int n_in,
                              void* d_out, int out_size, void* d_ws, size_t ws_size,
                              hipStream_t stream) {
    const float* x  = (const float*)d_in[0];
    const float* cb = (const float*)d_in[1];
    float* out = (float*)d_out;

    char* ws = (char*)d_ws;
    _Float16* cbh   = (_Float16*)(ws + WS_CBH);
    _Float16* cbl   = (_Float16*)(ws + WS_CBL);
    float*    c2    = (float*)(ws + WS_C2);
    int*      hist  = (int*)(ws + WS_HIST);
    float*    lpart = (float*)(ws + WS_LPART);
    unsigned short* idx = (unsigned short*)(ws + WS_IDX);

    (void)hipMemsetAsync(hist, 0, K * sizeof(int), stream);

    prep_kernel<<<36, 256, 0, stream>>>(cb, cbh, cbl, c2);
    vq_core<<<NVEC / 64, 256, 0, stream>>>(x, cbh, cbl, c2, idx, hist, lpart);
    streams_kernel<<<NVEC / 64, 256, 0, stream>>>(x, cb, idx, out);
    final_kernel<<<1, 1024, 0, stream>>>(hist, lpart, out);
}